// Round 12
// baseline (153.064 us; speedup 1.0000x reference)
//
#include <hip/hip_runtime.h>

// AnatomicalConsistencyLoss: fused separable-Sobel magnitude + cosine loss.
// pred/target (2,1,160,160,160) f32 -> scalar f32.
// R12 = R11 (f4 misaligned row loads, streaming pending-sum, XCD-chunked
// swizzle, fused transcendentals) + R9's 2-deep ping-pong prefetch, now
// affordable because a PF set is only 24 dwords (R9's was 48 w/ edge
// scalars -> 176 VGPR; R10 fixed that). Each set gets a FULL plane-step of
// latency cover; in-order VMEM lets the compiler wait on the older set with
// counted vmcnt while the newer stays in flight. Barrier-free main loop.

constexpr int Dd = 160, Hh = 160, Ww = 160;
constexpr int TW = 32, TH = 16, DC = 8;
constexpr int NTX = Ww / TW;                 // 5
constexpr int NTY = Hh / TH;                 // 10
constexpr int NTZ = Dd / DC;                 // 20
constexpr int NBLOCKS = NTX * NTY * NTZ * 2; // 2000
constexpr int NXCD = 8;
constexpr int CHUNK = NBLOCKS / NXCD;        // 250 (2000 % 8 == 0: bijective)
constexpr int PLANES = DC + 2;               // 10 (even: x2 unroll)
constexpr int PLSZ = Hh * Ww;                // 25600
constexpr double NVOX = 2.0 * Dd * Hh * Ww;  // 8,192,000

// 4-byte-aligned float4: hardware supports dword-aligned global_load_dwordx4.
typedef float f4 __attribute__((ext_vector_type(4), aligned(4)));

__device__ __forceinline__ float2 sm3f2(const float2 a, const float2 b, const float2 c) {
    return make_float2(a.x + 2.f*b.x + c.x, a.y + 2.f*b.y + c.y);
}
__device__ __forceinline__ float2 df2f2(const float2 a, const float2 c) {
    return make_float2(c.x - a.x, c.y - a.y);
}
__device__ __forceinline__ float2 add2(const float2 a, const float2 b) {
    return make_float2(a.x + b.x, a.y + b.y);
}
__device__ __forceinline__ float2 fma2s(const float2 a, const float s, const float2 b) {
    return make_float2(fmaf(a.x, s, b.x), fmaf(a.y, s, b.y));
}
__device__ __forceinline__ float2 neg2(const float2 a) {
    return make_float2(-a.x, -a.y);
}

// horizontal combos from raw span e = [e(X-1), e(X), e(X+1), e(X+2)]
__device__ __forceinline__ void comboF4(const f4 e, float2& HS, float2& HD) {
    HS = make_float2(e.x + 2.f*e.y + e.z, e.y + 2.f*e.z + e.w);
    HD = make_float2(e.z - e.x, e.w - e.y);
}

struct PF {   // one plane's prefetched rows, both volumes (24 dwords)
    f4 mP, cP, pP, mT, cT, pT;
};

__attribute__((amdgpu_waves_per_eu(4)))
__global__ __launch_bounds__(256)
void acl_partial(const float* __restrict__ pred, const float* __restrict__ targ,
                 float2* __restrict__ partial)
{
    __shared__ float rred[8];   // final reduction only; no LDS in main loop

    const int tid = threadIdx.x;
    const int gx = tid & 15;          // x-group of 2 output cols
    const int r  = tid >> 4;          // row 0..15

    // ---- XCD-chunked bijective swizzle + decode (zt fastest, wt, ht, b) ----
    const int bid  = blockIdx.x;
    const int swz  = (bid % NXCD) * CHUNK + bid / NXCD;   // XCD k owns [k*250,...)
    const int zt   = swz % NTZ;
    const int t1   = swz / NTZ;          // 0..99
    const int wt   = t1 % NTX;
    const int t2   = t1 / NTX;           // 0..19
    const int ht   = t2 % NTY;
    const int b    = t2 / NTY;           // 0..1

    const int x0 = wt * TW, y0 = ht * TH;
    const int z0 = zt * DC;
    const size_t base = (size_t)b * ((size_t)Dd * PLSZ);
    const float* __restrict__ pv = pred + base;
    const float* __restrict__ tv = targ + base;

    const int X = x0 + 2 * gx;
    const bool blkLo = (x0 == 0);
    const bool blkHi = (x0 + TW == Ww);
    const bool fixLo = blkLo && (gx == 0);    // load clamped +1, shift-right fixup
    const bool fixHi = blkHi && (gx == 15);   // load clamped -1, shift-left fixup
    const int xoff = X - 1 + (fixLo ? 1 : 0) - (fixHi ? 1 : 0);

    const int gym = y0 + r - 1;
    const int gyp = y0 + r + 1;
    const bool yokm = (gym >= 0);
    const bool yokp = (gyp < Hh);
    const int om = gym * Ww + xoff;
    const int oc = (y0 + r) * Ww + xoff;
    const int op = gyp * Ww + xoff;

    const float2 z2 = make_float2(0.f, 0.f);
    const f4 z4 = {0.f, 0.f, 0.f, 0.f};

    // streaming pending partial gradients (named scalars only)
    float2 P1x = z2, P1y = z2, P1z = z2, P2x = z2, P2y = z2, P2z = z2;  // pred
    float2 T1x = z2, T1y = z2, T1z = z2, T2x = z2, T2y = z2, T2z = z2;  // targ
    float2 accm = z2, accc = z2;

    auto issue = [&](PF& f, int p) {
        const int gz = z0 - 1 + p;
        f.mP = f.cP = f.pP = f.mT = f.cT = f.pT = z4;
        if ((unsigned)gz < (unsigned)Dd) {            // wave-uniform
            const float* pz = pv + (ptrdiff_t)gz * PLSZ;
            const float* tz = tv + (ptrdiff_t)gz * PLSZ;
            if (yokm) { f.mP = *(const f4*)(pz + om); f.mT = *(const f4*)(tz + om); }
            f.cP = *(const f4*)(pz + oc);  f.cT = *(const f4*)(tz + oc);
            if (yokp) { f.pP = *(const f4*)(pz + op); f.pT = *(const f4*)(tz + op); }
        }
    };

    // volume-edge fixup: only edge blocks pay (block-uniform branches)
    auto fixup = [&](f4 v) -> f4 {
        if (blkLo) { const f4 s = {0.f, v.x, v.y, v.z}; if (fixLo) v = s; }
        if (blkHi) { const f4 s = {v.y, v.z, v.w, 0.f}; if (fixHi) v = s; }
        return v;
    };

    auto consumeVol = [&](f4 m, f4 c, f4 p, float2& A, float2& B, float2& C) {
        m = fixup(m); c = fixup(c); p = fixup(p);
        float2 HSm, HDm, HS0, HD0, HSp, HDp;
        comboF4(m, HSm, HDm);
        comboF4(c, HS0, HD0);
        comboF4(p, HSp, HDp);
        A = sm3f2(HSm, HS0, HSp);   // sm_y(sm_x) -> z-deriv path
        B = sm3f2(HDm, HD0, HDp);   // sm_y(d_x)  -> x-gradient
        C = df2f2(HSm, HSp);        // d_y(sm_x)  -> y-gradient
    };

    auto step = [&](PF& f, int p) {
        float2 A, B, C;
        consumeVol(f.mP, f.cP, f.pP, A, B, C);
        const float2 fpx = add2(P1x, B), fpy = add2(P1y, C), fpz = add2(P1z, A);
        P1x = fma2s(B, 2.f, P2x);  P1y = fma2s(C, 2.f, P2y);  P1z = P2z;
        P2x = B;  P2y = C;  P2z = neg2(A);

        consumeVol(f.mT, f.cT, f.pT, A, B, C);
        const float2 ftx = add2(T1x, B), fty = add2(T1y, C), ftz = add2(T1z, A);
        T1x = fma2s(B, 2.f, T2x);  T1y = fma2s(C, 2.f, T2y);  T1z = T2z;
        T2x = B;  T2y = C;  T2z = neg2(A);

        if (p >= 2) {   // output plane z0 + (p-2) finalized
            // fused: (pm-tm)^2 = a+b-2*sqrt(a*b);  rsq(np2)*rsq(nt2)=rsq(np2*nt2)
            #define LOSS_COMP(c)                                                  \
            {                                                                     \
                const float np2 = fpx.c*fpx.c + fpy.c*fpy.c + fpz.c*fpz.c;        \
                const float nt2 = ftx.c*ftx.c + fty.c*fty.c + ftz.c*ftz.c;        \
                const float a = np2 + 1e-8f, bb = nt2 + 1e-8f;                    \
                accm.c += a + bb - 2.f * __builtin_amdgcn_sqrtf(a * bb);          \
                const float dt = fpx.c*ftx.c + fpy.c*fty.c + fpz.c*ftz.c;         \
                const float pr = fmaxf(np2 * nt2, 1e-30f);                        \
                accc.c += dt * __builtin_amdgcn_rsqf(pr);                         \
            }
            LOSS_COMP(x)
            LOSS_COMP(y)
            #undef LOSS_COMP
        }
    };

    PF f0, f1;
    issue(f0, 0);      // in flight during prologue + f1 issue
    issue(f1, 1);

    #pragma unroll
    for (int pp = 0; pp < PLANES; pp += 2) {   // 2-deep ping-pong: full-step cover
        step(f0, pp);
        if (pp + 2 < PLANES) issue(f0, pp + 2);
        step(f1, pp + 1);
        if (pp + 3 < PLANES) issue(f1, pp + 3);
    }

    // ---- block reduction (only sync in the kernel) ----
    float am = accm.x + accm.y;
    float ac = accc.x + accc.y;
    #pragma unroll
    for (int off = 32; off >= 1; off >>= 1) {
        am += __shfl_down(am, off);
        ac += __shfl_down(ac, off);
    }
    const int wid = tid >> 6;
    if ((tid & 63) == 0) { rred[wid] = am; rred[4 + wid] = ac; }
    __syncthreads();
    if (tid == 0) {
        const float m = rred[0] + rred[1] + rred[2] + rred[3];
        const float c = rred[4] + rred[5] + rred[6] + rred[7];
        partial[bid] = make_float2(m, c);   // unique slot per block
    }
}

__global__ __launch_bounds__(256)
void acl_final(const float2* __restrict__ partial, float* __restrict__ out)
{
    __shared__ double sm[256], sc[256];
    double m = 0.0, c = 0.0;
    for (int i = threadIdx.x; i < NBLOCKS; i += 256) {
        const float2 v = partial[i];
        m += (double)v.x;
        c += (double)v.y;
    }
    sm[threadIdx.x] = m;
    sc[threadIdx.x] = c;
    __syncthreads();
    #pragma unroll
    for (int s = 128; s >= 1; s >>= 1) {
        if (threadIdx.x < (unsigned)s) {
            sm[threadIdx.x] += sm[threadIdx.x + s];
            sc[threadIdx.x] += sc[threadIdx.x + s];
        }
        __syncthreads();
    }
    if (threadIdx.x == 0) {
        const double mag_loss = sm[0] / NVOX;
        const double dir_loss = 1.0 - sc[0] / NVOX;
        out[0] = (float)(0.2 * (mag_loss + dir_loss));
    }
}

extern "C" void kernel_launch(void* const* d_in, const int* in_sizes, int n_in,
                              void* d_out, int out_size, void* d_ws, size_t ws_size,
                              hipStream_t stream) {
    const float* pred = (const float*)d_in[0];
    const float* targ = (const float*)d_in[1];
    float* out = (float*)d_out;
    float2* partial = (float2*)d_ws;  // 2000 * 8 B = 16 KB

    acl_partial<<<NBLOCKS, 256, 0, stream>>>(pred, targ, partial);
    acl_final<<<1, 256, 0, stream>>>(partial, out);
}

// Round 13
// 38.592 us; speedup vs baseline: 3.9662x; 3.9662x over previous
//
#include <hip/hip_runtime.h>

// AnatomicalConsistencyLoss: fused separable-Sobel magnitude + cosine loss.
// pred/target (2,1,160,160,160) f32 -> scalar f32.
// R13 = R11 structure EXACTLY (barrier-free, f4 misaligned row loads,
// half-plane software pipeline, streaming pending-sum, XCD-chunked swizzle,
// fused transcendentals; 44 VGPR / no spill proven) with the arithmetic
// rewritten as native ext_vector_type(2) ops so the backend emits packed
// dual-f32 VOP3P (v_pk_fma_f32 etc.) -- R12 proved deeper prefetch triggers
// the allocator's spill heuristic, so the remaining lever is VALU count:
// ~5400 busy-cycles/wave ~= 17.5us floor at 100% issue; packing cuts the
// stencil+stream section ~2x. z-pending recurrence refactored to drop the
// negate (P2z = A; fpz = A - P1z).

constexpr int Dd = 160, Hh = 160, Ww = 160;
constexpr int TW = 32, TH = 16, DC = 8;
constexpr int NTX = Ww / TW;                 // 5
constexpr int NTY = Hh / TH;                 // 10
constexpr int NTZ = Dd / DC;                 // 20
constexpr int NBLOCKS = NTX * NTY * NTZ * 2; // 2000
constexpr int NXCD = 8;
constexpr int CHUNK = NBLOCKS / NXCD;        // 250 (2000 % 8 == 0: bijective)
constexpr int PLANES = DC + 2;               // 10
constexpr int PLSZ = Hh * Ww;                // 25600
constexpr double NVOX = 2.0 * Dd * Hh * Ww;  // 8,192,000

// native clang vectors: v2 arithmetic lowers to packed dual-f32 VOP3P
typedef float v2 __attribute__((ext_vector_type(2)));
typedef float v4 __attribute__((ext_vector_type(4), aligned(4)));  // dword-aligned dwordx4

__attribute__((amdgpu_waves_per_eu(4)))
__global__ __launch_bounds__(256)
void acl_partial(const float* __restrict__ pred, const float* __restrict__ targ,
                 float2* __restrict__ partial)
{
    __shared__ float rred[8];   // final reduction only; no LDS in main loop

    const int tid = threadIdx.x;
    const int gx = tid & 15;          // x-group of 2 output cols
    const int r  = tid >> 4;          // row 0..15

    // ---- XCD-chunked bijective swizzle + decode (zt fastest, wt, ht, b) ----
    const int bid  = blockIdx.x;
    const int swz  = (bid % NXCD) * CHUNK + bid / NXCD;   // XCD k owns [k*250,...)
    const int zt   = swz % NTZ;
    const int t1   = swz / NTZ;          // 0..99
    const int wt   = t1 % NTX;
    const int t2   = t1 / NTX;           // 0..19
    const int ht   = t2 % NTY;
    const int b    = t2 / NTY;           // 0..1

    const int x0 = wt * TW, y0 = ht * TH;
    const int z0 = zt * DC;
    const size_t base = (size_t)b * ((size_t)Dd * PLSZ);
    const float* __restrict__ pv = pred + base;
    const float* __restrict__ tv = targ + base;

    const int X = x0 + 2 * gx;
    const bool blkLo = (x0 == 0);
    const bool blkHi = (x0 + TW == Ww);
    const bool fixLo = blkLo && (gx == 0);    // load clamped +1, shift-right fixup
    const bool fixHi = blkHi && (gx == 15);   // load clamped -1, shift-left fixup
    const int xoff = X - 1 + (fixLo ? 1 : 0) - (fixHi ? 1 : 0);

    const int gym = y0 + r - 1;
    const int gyp = y0 + r + 1;
    const bool yokm = (gym >= 0);
    const bool yokp = (gyp < Hh);
    const int om = gym * Ww + xoff;
    const int oc = (y0 + r) * Ww + xoff;
    const int op = gyp * Ww + xoff;

    const v2 z2 = {0.f, 0.f};
    const v4 z4 = {0.f, 0.f, 0.f, 0.f};

    // streaming pending partial gradients (named v2 scalars only)
    v2 P1x = z2, P1y = z2, P1z = z2, P2x = z2, P2y = z2, P2z = z2;  // pred
    v2 T1x = z2, T1y = z2, T1z = z2, T2x = z2, T2y = z2, T2z = z2;  // targ
    v2 accm = z2, accc = z2;

    // prefetch registers: 3 rows per volume (24 dwords total)
    v4 mP, cP, pP, mT, cT, pT;

    auto issueP = [&](int p) {
        const int gz = z0 - 1 + p;
        mP = cP = pP = z4;
        if ((unsigned)gz < (unsigned)Dd) {            // wave-uniform
            const float* pz = pv + (ptrdiff_t)gz * PLSZ;
            if (yokm) mP = *(const v4*)(pz + om);
            cP = *(const v4*)(pz + oc);
            if (yokp) pP = *(const v4*)(pz + op);
        }
    };
    auto issueT = [&](int p) {
        const int gz = z0 - 1 + p;
        mT = cT = pT = z4;
        if ((unsigned)gz < (unsigned)Dd) {
            const float* tz = tv + (ptrdiff_t)gz * PLSZ;
            if (yokm) mT = *(const v4*)(tz + om);
            cT = *(const v4*)(tz + oc);
            if (yokp) pT = *(const v4*)(tz + op);
        }
    };

    // volume-edge fixup: only edge blocks pay (block-uniform branches)
    auto fixup = [&](v4 v) -> v4 {
        if (blkLo) { const v4 s = {0.f, v.x, v.y, v.z}; if (fixLo) v = s; }
        if (blkHi) { const v4 s = {v.y, v.z, v.w, 0.f}; if (fixHi) v = s; }
        return v;
    };

    // horizontal + vertical combos, all packed v2 arithmetic
    auto consumeVol = [&](v4 m, v4 c, v4 p, v2& A, v2& B, v2& C) {
        m = fixup(m); c = fixup(c); p = fixup(p);
        const v2 HSm = m.xy + 2.f*m.yz + m.zw;   // smooth_x, row y-1
        const v2 HDm = m.zw - m.xy;              // deriv_x,  row y-1
        const v2 HS0 = c.xy + 2.f*c.yz + c.zw;
        const v2 HD0 = c.zw - c.xy;
        const v2 HSp = p.xy + 2.f*p.yz + p.zw;
        const v2 HDp = p.zw - p.xy;
        A = HSm + 2.f*HS0 + HSp;   // sm_y(sm_x) -> z-deriv path
        B = HDm + 2.f*HD0 + HDp;   // sm_y(d_x)  -> x-gradient
        C = HSp - HSm;             // d_y(sm_x)  -> y-gradient
    };

    issueP(0);

    for (int p = 0; p < PLANES; ++p) {
        issueT(p);                      // targ loads fly under pred consume

        v2 A, B, C;
        consumeVol(mP, cP, pP, A, B, C);
        const v2 fpx = P1x + B, fpy = P1y + C, fpz = A - P1z;
        P1x = 2.f*B + P2x;  P1y = 2.f*C + P2y;  P1z = P2z;
        P2x = B;  P2y = C;  P2z = A;

        if (p + 1 < PLANES) issueP(p + 1);   // next pred flies under targ consume

        consumeVol(mT, cT, pT, A, B, C);
        const v2 ftx = T1x + B, fty = T1y + C, ftz = A - T1z;
        T1x = 2.f*B + T2x;  T1y = 2.f*C + T2y;  T1z = T2z;
        T2x = B;  T2y = C;  T2z = A;

        if (p >= 2) {   // output plane z0 + (p-2) finalized
            // fused: (pm-tm)^2 = a+b-2*sqrt(a*b);  rsq(np2)*rsq(nt2)=rsq(np2*nt2)
            #define LOSS_COMP(c)                                                  \
            {                                                                     \
                const float np2 = fpx.c*fpx.c + fpy.c*fpy.c + fpz.c*fpz.c;        \
                const float nt2 = ftx.c*ftx.c + fty.c*fty.c + ftz.c*ftz.c;        \
                const float a = np2 + 1e-8f, bb = nt2 + 1e-8f;                    \
                accm.c += a + bb - 2.f * __builtin_amdgcn_sqrtf(a * bb);          \
                const float dt = fpx.c*ftx.c + fpy.c*fty.c + fpz.c*ftz.c;         \
                const float pr = fmaxf(np2 * nt2, 1e-30f);                        \
                accc.c += dt * __builtin_amdgcn_rsqf(pr);                         \
            }
            LOSS_COMP(x)
            LOSS_COMP(y)
            #undef LOSS_COMP
        }
    }

    // ---- block reduction (only sync in the kernel) ----
    float am = accm.x + accm.y;
    float ac = accc.x + accc.y;
    #pragma unroll
    for (int off = 32; off >= 1; off >>= 1) {
        am += __shfl_down(am, off);
        ac += __shfl_down(ac, off);
    }
    const int wid = tid >> 6;
    if ((tid & 63) == 0) { rred[wid] = am; rred[4 + wid] = ac; }
    __syncthreads();
    if (tid == 0) {
        const float m = rred[0] + rred[1] + rred[2] + rred[3];
        const float c = rred[4] + rred[5] + rred[6] + rred[7];
        partial[bid] = make_float2(m, c);   // unique slot per block
    }
}

__global__ __launch_bounds__(256)
void acl_final(const float2* __restrict__ partial, float* __restrict__ out)
{
    __shared__ double sm[256], sc[256];
    double m = 0.0, c = 0.0;
    for (int i = threadIdx.x; i < NBLOCKS; i += 256) {
        const float2 v = partial[i];
        m += (double)v.x;
        c += (double)v.y;
    }
    sm[threadIdx.x] = m;
    sc[threadIdx.x] = c;
    __syncthreads();
    #pragma unroll
    for (int s = 128; s >= 1; s >>= 1) {
        if (threadIdx.x < (unsigned)s) {
            sm[threadIdx.x] += sm[threadIdx.x + s];
            sc[threadIdx.x] += sc[threadIdx.x + s];
        }
        __syncthreads();
    }
    if (threadIdx.x == 0) {
        const double mag_loss = sm[0] / NVOX;
        const double dir_loss = 1.0 - sc[0] / NVOX;
        out[0] = (float)(0.2 * (mag_loss + dir_loss));
    }
}

extern "C" void kernel_launch(void* const* d_in, const int* in_sizes, int n_in,
                              void* d_out, int out_size, void* d_ws, size_t ws_size,
                              hipStream_t stream) {
    const float* pred = (const float*)d_in[0];
    const float* targ = (const float*)d_in[1];
    float* out = (float*)d_out;
    float2* partial = (float2*)d_ws;  // 2000 * 8 B = 16 KB

    acl_partial<<<NBLOCKS, 256, 0, stream>>>(pred, targ, partial);
    acl_final<<<1, 256, 0, stream>>>(partial, out);
}

// Round 14
// 36.593 us; speedup vs baseline: 4.1829x; 1.0546x over previous
//
#include <hip/hip_runtime.h>

// AnatomicalConsistencyLoss: fused separable-Sobel magnitude + cosine loss.
// pred/target (2,1,160,160,160) f32 -> scalar f32.
// R14 = R13 with DC 8->16: halves the warm-up overhead (2 non-output planes
// per block: 25% -> 12.5% of all work) and cuts z-halo overfetch (1.25x ->
// 1.125x plane redundancy). 1000 blocks (~15.6 waves/CU, same effective TLP
// as measured). Loss-tail math rewritten in packed v2 (was the last scalar
// section). Everything else byte-identical to the proven 44-VGPR no-spill
// structure: barrier-free loop, f4 misaligned row loads, half-plane software
// pipeline, streaming pending-sum, XCD-chunked bijective swizzle, fused
// transcendentals.

constexpr int Dd = 160, Hh = 160, Ww = 160;
constexpr int TW = 32, TH = 16, DC = 16;
constexpr int NTX = Ww / TW;                 // 5
constexpr int NTY = Hh / TH;                 // 10
constexpr int NTZ = Dd / DC;                 // 10
constexpr int NBLOCKS = NTX * NTY * NTZ * 2; // 1000
constexpr int NXCD = 8;
constexpr int CHUNK = NBLOCKS / NXCD;        // 125 (1000 % 8 == 0: bijective)
constexpr int PLANES = DC + 2;               // 18
constexpr int PLSZ = Hh * Ww;                // 25600
constexpr double NVOX = 2.0 * Dd * Hh * Ww;  // 8,192,000

// native clang vectors: v2 arithmetic lowers to packed dual-f32 VOP3P
typedef float v2 __attribute__((ext_vector_type(2)));
typedef float v4 __attribute__((ext_vector_type(4), aligned(4)));  // dword-aligned dwordx4

__attribute__((amdgpu_waves_per_eu(4)))
__global__ __launch_bounds__(256)
void acl_partial(const float* __restrict__ pred, const float* __restrict__ targ,
                 float2* __restrict__ partial)
{
    __shared__ float rred[8];   // final reduction only; no LDS in main loop

    const int tid = threadIdx.x;
    const int gx = tid & 15;          // x-group of 2 output cols
    const int r  = tid >> 4;          // row 0..15

    // ---- XCD-chunked bijective swizzle + decode (zt fastest, wt, ht, b) ----
    const int bid  = blockIdx.x;
    const int swz  = (bid % NXCD) * CHUNK + bid / NXCD;   // XCD k owns [k*125,...)
    const int zt   = swz % NTZ;
    const int t1   = swz / NTZ;          // 0..99
    const int wt   = t1 % NTX;
    const int t2   = t1 / NTX;           // 0..19
    const int ht   = t2 % NTY;
    const int b    = t2 / NTY;           // 0..1

    const int x0 = wt * TW, y0 = ht * TH;
    const int z0 = zt * DC;
    const size_t base = (size_t)b * ((size_t)Dd * PLSZ);
    const float* __restrict__ pv = pred + base;
    const float* __restrict__ tv = targ + base;

    const int X = x0 + 2 * gx;
    const bool blkLo = (x0 == 0);
    const bool blkHi = (x0 + TW == Ww);
    const bool fixLo = blkLo && (gx == 0);    // load clamped +1, shift-right fixup
    const bool fixHi = blkHi && (gx == 15);   // load clamped -1, shift-left fixup
    const int xoff = X - 1 + (fixLo ? 1 : 0) - (fixHi ? 1 : 0);

    const int gym = y0 + r - 1;
    const int gyp = y0 + r + 1;
    const bool yokm = (gym >= 0);
    const bool yokp = (gyp < Hh);
    const int om = gym * Ww + xoff;
    const int oc = (y0 + r) * Ww + xoff;
    const int op = gyp * Ww + xoff;

    const v2 z2 = {0.f, 0.f};
    const v4 z4 = {0.f, 0.f, 0.f, 0.f};

    // streaming pending partial gradients (named v2 scalars only)
    v2 P1x = z2, P1y = z2, P1z = z2, P2x = z2, P2y = z2, P2z = z2;  // pred
    v2 T1x = z2, T1y = z2, T1z = z2, T2x = z2, T2y = z2, T2z = z2;  // targ
    v2 accm = z2, accc = z2;

    // prefetch registers: 3 rows per volume (24 dwords total)
    v4 mP, cP, pP, mT, cT, pT;

    auto issueP = [&](int p) {
        const int gz = z0 - 1 + p;
        mP = cP = pP = z4;
        if ((unsigned)gz < (unsigned)Dd) {            // wave-uniform
            const float* pz = pv + (ptrdiff_t)gz * PLSZ;
            if (yokm) mP = *(const v4*)(pz + om);
            cP = *(const v4*)(pz + oc);
            if (yokp) pP = *(const v4*)(pz + op);
        }
    };
    auto issueT = [&](int p) {
        const int gz = z0 - 1 + p;
        mT = cT = pT = z4;
        if ((unsigned)gz < (unsigned)Dd) {
            const float* tz = tv + (ptrdiff_t)gz * PLSZ;
            if (yokm) mT = *(const v4*)(tz + om);
            cT = *(const v4*)(tz + oc);
            if (yokp) pT = *(const v4*)(tz + op);
        }
    };

    // volume-edge fixup: only edge blocks pay (block-uniform branches)
    auto fixup = [&](v4 v) -> v4 {
        if (blkLo) { const v4 s = {0.f, v.x, v.y, v.z}; if (fixLo) v = s; }
        if (blkHi) { const v4 s = {v.y, v.z, v.w, 0.f}; if (fixHi) v = s; }
        return v;
    };

    // horizontal + vertical combos, packed v2 arithmetic
    auto consumeVol = [&](v4 m, v4 c, v4 p, v2& A, v2& B, v2& C) {
        m = fixup(m); c = fixup(c); p = fixup(p);
        const v2 HSm = m.xy + 2.f*m.yz + m.zw;   // smooth_x, row y-1
        const v2 HDm = m.zw - m.xy;              // deriv_x,  row y-1
        const v2 HS0 = c.xy + 2.f*c.yz + c.zw;
        const v2 HD0 = c.zw - c.xy;
        const v2 HSp = p.xy + 2.f*p.yz + p.zw;
        const v2 HDp = p.zw - p.xy;
        A = HSm + 2.f*HS0 + HSp;   // sm_y(sm_x) -> z-deriv path
        B = HDm + 2.f*HD0 + HDp;   // sm_y(d_x)  -> x-gradient
        C = HSp - HSm;             // d_y(sm_x)  -> y-gradient
    };

    issueP(0);

    for (int p = 0; p < PLANES; ++p) {
        issueT(p);                      // targ loads fly under pred consume

        v2 A, B, C;
        consumeVol(mP, cP, pP, A, B, C);
        const v2 fpx = P1x + B, fpy = P1y + C, fpz = A - P1z;
        P1x = 2.f*B + P2x;  P1y = 2.f*C + P2y;  P1z = P2z;
        P2x = B;  P2y = C;  P2z = A;

        if (p + 1 < PLANES) issueP(p + 1);   // next pred flies under targ consume

        consumeVol(mT, cT, pT, A, B, C);
        const v2 ftx = T1x + B, fty = T1y + C, ftz = A - T1z;
        T1x = 2.f*B + T2x;  T1y = 2.f*C + T2y;  T1z = T2z;
        T2x = B;  T2y = C;  T2z = A;

        if (p >= 2) {   // output plane z0 + (p-2) finalized
            // fused: (pm-tm)^2 = a+b-2*sqrt(a*b);  rsq(np2)*rsq(nt2)=rsq(np2*nt2)
            // all tail math in packed v2; only sqrt/rsq are scalar (no pk trans)
            const v2 np2 = fpx*fpx + fpy*fpy + fpz*fpz;
            const v2 nt2 = ftx*ftx + fty*fty + ftz*ftz;
            const v2 a  = np2 + 1e-8f;
            const v2 bb = nt2 + 1e-8f;
            const v2 ab = a * bb;
            v2 rt;
            rt.x = __builtin_amdgcn_sqrtf(ab.x);
            rt.y = __builtin_amdgcn_sqrtf(ab.y);
            accm += a + bb - 2.f*rt;
            const v2 dt = fpx*ftx + fpy*fty + fpz*ftz;
            v2 pr = np2 * nt2;
            pr.x = fmaxf(pr.x, 1e-30f);
            pr.y = fmaxf(pr.y, 1e-30f);
            v2 rq;
            rq.x = __builtin_amdgcn_rsqf(pr.x);
            rq.y = __builtin_amdgcn_rsqf(pr.y);
            accc += dt * rq;
        }
    }

    // ---- block reduction (only sync in the kernel) ----
    float am = accm.x + accm.y;
    float ac = accc.x + accc.y;
    #pragma unroll
    for (int off = 32; off >= 1; off >>= 1) {
        am += __shfl_down(am, off);
        ac += __shfl_down(ac, off);
    }
    const int wid = tid >> 6;
    if ((tid & 63) == 0) { rred[wid] = am; rred[4 + wid] = ac; }
    __syncthreads();
    if (tid == 0) {
        const float m = rred[0] + rred[1] + rred[2] + rred[3];
        const float c = rred[4] + rred[5] + rred[6] + rred[7];
        partial[bid] = make_float2(m, c);   // unique slot per block
    }
}

__global__ __launch_bounds__(256)
void acl_final(const float2* __restrict__ partial, float* __restrict__ out)
{
    __shared__ double sm[256], sc[256];
    double m = 0.0, c = 0.0;
    for (int i = threadIdx.x; i < NBLOCKS; i += 256) {
        const float2 v = partial[i];
        m += (double)v.x;
        c += (double)v.y;
    }
    sm[threadIdx.x] = m;
    sc[threadIdx.x] = c;
    __syncthreads();
    #pragma unroll
    for (int s = 128; s >= 1; s >>= 1) {
        if (threadIdx.x < (unsigned)s) {
            sm[threadIdx.x] += sm[threadIdx.x + s];
            sc[threadIdx.x] += sc[threadIdx.x + s];
        }
        __syncthreads();
    }
    if (threadIdx.x == 0) {
        const double mag_loss = sm[0] / NVOX;
        const double dir_loss = 1.0 - sc[0] / NVOX;
        out[0] = (float)(0.2 * (mag_loss + dir_loss));
    }
}

extern "C" void kernel_launch(void* const* d_in, const int* in_sizes, int n_in,
                              void* d_out, int out_size, void* d_ws, size_t ws_size,
                              hipStream_t stream) {
    const float* pred = (const float*)d_in[0];
    const float* targ = (const float*)d_in[1];
    float* out = (float*)d_out;
    float2* partial = (float2*)d_ws;  // 1000 * 8 B = 8 KB

    acl_partial<<<NBLOCKS, 256, 0, stream>>>(pred, targ, partial);
    acl_final<<<1, 256, 0, stream>>>(partial, out);
}

// Round 15
// 34.041 us; speedup vs baseline: 4.4965x; 1.0750x over previous
//
#include <hip/hip_runtime.h>

// AnatomicalConsistencyLoss: fused separable-Sobel magnitude + cosine loss.
// pred/target (2,1,160,160,160) f32 -> scalar f32.
// R15 = R14 with two VALU/latency fixes, zero new live state:
// (1) zero-init hoisted out of the loop: yokm/yokp are loop-invariant, so
//     invalid-row lanes zeroed ONCE stay zero; issue() only branches on the
//     uniform z-guard (zero path only on boundary planes of edge-zt blocks).
//     Removes ~24 dead v_movs/plane (~25% of loop VALU).
// (2) balanced prefetch: consume-then-reissue per volume set (P then T), so
//     BOTH sets get ~3/4-iteration latency cover (was 200cy/80cy skewed).
//     Same 24-dword PF state -- no R12-style allocator provocation.
// Everything else identical to R14: DC=16, barrier-free, f4 misaligned row
// loads, streaming pending-sum, XCD-chunked bijective swizzle, fused
// transcendentals, packed-v2 tail.

constexpr int Dd = 160, Hh = 160, Ww = 160;
constexpr int TW = 32, TH = 16, DC = 16;
constexpr int NTX = Ww / TW;                 // 5
constexpr int NTY = Hh / TH;                 // 10
constexpr int NTZ = Dd / DC;                 // 10
constexpr int NBLOCKS = NTX * NTY * NTZ * 2; // 1000
constexpr int NXCD = 8;
constexpr int CHUNK = NBLOCKS / NXCD;        // 125 (1000 % 8 == 0: bijective)
constexpr int PLANES = DC + 2;               // 18
constexpr int PLSZ = Hh * Ww;                // 25600
constexpr double NVOX = 2.0 * Dd * Hh * Ww;  // 8,192,000

// native clang vectors: v2 arithmetic lowers to packed dual-f32 VOP3P
typedef float v2 __attribute__((ext_vector_type(2)));
typedef float v4 __attribute__((ext_vector_type(4), aligned(4)));  // dword-aligned dwordx4

__attribute__((amdgpu_waves_per_eu(4)))
__global__ __launch_bounds__(256)
void acl_partial(const float* __restrict__ pred, const float* __restrict__ targ,
                 float2* __restrict__ partial)
{
    __shared__ float rred[8];   // final reduction only; no LDS in main loop

    const int tid = threadIdx.x;
    const int gx = tid & 15;          // x-group of 2 output cols
    const int r  = tid >> 4;          // row 0..15

    // ---- XCD-chunked bijective swizzle + decode (zt fastest, wt, ht, b) ----
    const int bid  = blockIdx.x;
    const int swz  = (bid % NXCD) * CHUNK + bid / NXCD;   // XCD k owns [k*125,...)
    const int zt   = swz % NTZ;
    const int t1   = swz / NTZ;          // 0..99
    const int wt   = t1 % NTX;
    const int t2   = t1 / NTX;           // 0..19
    const int ht   = t2 % NTY;
    const int b    = t2 / NTY;           // 0..1

    const int x0 = wt * TW, y0 = ht * TH;
    const int z0 = zt * DC;
    const size_t base = (size_t)b * ((size_t)Dd * PLSZ);
    const float* __restrict__ pv = pred + base;
    const float* __restrict__ tv = targ + base;

    const int X = x0 + 2 * gx;
    const bool blkLo = (x0 == 0);
    const bool blkHi = (x0 + TW == Ww);
    const bool fixLo = blkLo && (gx == 0);    // load clamped +1, shift-right fixup
    const bool fixHi = blkHi && (gx == 15);   // load clamped -1, shift-left fixup
    const int xoff = X - 1 + (fixLo ? 1 : 0) - (fixHi ? 1 : 0);

    const int gym = y0 + r - 1;
    const int gyp = y0 + r + 1;
    const bool yokm = (gym >= 0);     // loop-invariant per thread
    const bool yokp = (gyp < Hh);     // loop-invariant per thread
    const int om = gym * Ww + xoff;
    const int oc = (y0 + r) * Ww + xoff;
    const int op = gyp * Ww + xoff;

    const v2 z2 = {0.f, 0.f};
    const v4 z4 = {0.f, 0.f, 0.f, 0.f};

    // streaming pending partial gradients (named v2 scalars only)
    v2 P1x = z2, P1y = z2, P1z = z2, P2x = z2, P2y = z2, P2z = z2;  // pred
    v2 T1x = z2, T1y = z2, T1z = z2, T2x = z2, T2y = z2, T2z = z2;  // targ
    v2 accm = z2, accc = z2;

    // prefetch registers: 3 rows per volume (24 dwords). Zero-init ONCE:
    // lanes with !yokm (!yokp) are never loaded on any plane, so their m (p)
    // rows remain zero for the whole loop -- no per-plane re-zeroing needed.
    v4 mP = z4, cP = z4, pP = z4, mT = z4, cT = z4, pT = z4;

    auto issueP = [&](int p) {
        const int gz = z0 - 1 + p;
        if ((unsigned)gz < (unsigned)Dd) {            // wave-uniform branch
            const float* pz = pv + (ptrdiff_t)gz * PLSZ;
            if (yokm) mP = *(const v4*)(pz + om);
            cP = *(const v4*)(pz + oc);
            if (yokp) pP = *(const v4*)(pz + op);
        } else {   // only plane 0 of zt==0 / last plane of zt==NTZ-1
            mP = z4; cP = z4; pP = z4;
        }
    };
    auto issueT = [&](int p) {
        const int gz = z0 - 1 + p;
        if ((unsigned)gz < (unsigned)Dd) {
            const float* tz = tv + (ptrdiff_t)gz * PLSZ;
            if (yokm) mT = *(const v4*)(tz + om);
            cT = *(const v4*)(tz + oc);
            if (yokp) pT = *(const v4*)(tz + op);
        } else {
            mT = z4; cT = z4; pT = z4;
        }
    };

    // volume-edge fixup: only edge blocks pay (block-uniform branches)
    auto fixup = [&](v4 v) -> v4 {
        if (blkLo) { const v4 s = {0.f, v.x, v.y, v.z}; if (fixLo) v = s; }
        if (blkHi) { const v4 s = {v.y, v.z, v.w, 0.f}; if (fixHi) v = s; }
        return v;
    };

    // horizontal + vertical combos, packed v2 arithmetic
    auto consumeVol = [&](v4 m, v4 c, v4 p, v2& A, v2& B, v2& C) {
        m = fixup(m); c = fixup(c); p = fixup(p);
        const v2 HSm = m.xy + 2.f*m.yz + m.zw;   // smooth_x, row y-1
        const v2 HDm = m.zw - m.xy;              // deriv_x,  row y-1
        const v2 HS0 = c.xy + 2.f*c.yz + c.zw;
        const v2 HD0 = c.zw - c.xy;
        const v2 HSp = p.xy + 2.f*p.yz + p.zw;
        const v2 HDp = p.zw - p.xy;
        A = HSm + 2.f*HS0 + HSp;   // sm_y(sm_x) -> z-deriv path
        B = HDm + 2.f*HD0 + HDp;   // sm_y(d_x)  -> x-gradient
        C = HSp - HSm;             // d_y(sm_x)  -> y-gradient
    };

    issueP(0);
    issueT(0);

    for (int p = 0; p < PLANES; ++p) {
        v2 A, B, C;

        // ---- pred: consume, then immediately refill the SAME set for p+1
        //      (loads get ~3/4 iteration of cover; live state unchanged) ----
        consumeVol(mP, cP, pP, A, B, C);
        const v2 fpx = P1x + B, fpy = P1y + C, fpz = A - P1z;
        P1x = 2.f*B + P2x;  P1y = 2.f*C + P2y;  P1z = P2z;
        P2x = B;  P2y = C;  P2z = A;
        if (p + 1 < PLANES) issueP(p + 1);

        // ---- targ: same pattern ----
        consumeVol(mT, cT, pT, A, B, C);
        const v2 ftx = T1x + B, fty = T1y + C, ftz = A - T1z;
        T1x = 2.f*B + T2x;  T1y = 2.f*C + T2y;  T1z = T2z;
        T2x = B;  T2y = C;  T2z = A;
        if (p + 1 < PLANES) issueT(p + 1);

        if (p >= 2) {   // output plane z0 + (p-2) finalized
            // fused: (pm-tm)^2 = a+b-2*sqrt(a*b);  rsq(np2)*rsq(nt2)=rsq(np2*nt2)
            const v2 np2 = fpx*fpx + fpy*fpy + fpz*fpz;
            const v2 nt2 = ftx*ftx + fty*fty + ftz*ftz;
            const v2 a  = np2 + 1e-8f;
            const v2 bb = nt2 + 1e-8f;
            const v2 ab = a * bb;
            v2 rt;
            rt.x = __builtin_amdgcn_sqrtf(ab.x);
            rt.y = __builtin_amdgcn_sqrtf(ab.y);
            accm += a + bb - 2.f*rt;
            const v2 dt = fpx*ftx + fpy*fty + fpz*ftz;
            v2 pr = np2 * nt2;
            pr.x = fmaxf(pr.x, 1e-30f);
            pr.y = fmaxf(pr.y, 1e-30f);
            v2 rq;
            rq.x = __builtin_amdgcn_rsqf(pr.x);
            rq.y = __builtin_amdgcn_rsqf(pr.y);
            accc += dt * rq;
        }
    }

    // ---- block reduction (only sync in the kernel) ----
    float am = accm.x + accm.y;
    float ac = accc.x + accc.y;
    #pragma unroll
    for (int off = 32; off >= 1; off >>= 1) {
        am += __shfl_down(am, off);
        ac += __shfl_down(ac, off);
    }
    const int wid = tid >> 6;
    if ((tid & 63) == 0) { rred[wid] = am; rred[4 + wid] = ac; }
    __syncthreads();
    if (tid == 0) {
        const float m = rred[0] + rred[1] + rred[2] + rred[3];
        const float c = rred[4] + rred[5] + rred[6] + rred[7];
        partial[bid] = make_float2(m, c);   // unique slot per block
    }
}

__global__ __launch_bounds__(256)
void acl_final(const float2* __restrict__ partial, float* __restrict__ out)
{
    __shared__ double sm[256], sc[256];
    double m = 0.0, c = 0.0;
    for (int i = threadIdx.x; i < NBLOCKS; i += 256) {
        const float2 v = partial[i];
        m += (double)v.x;
        c += (double)v.y;
    }
    sm[threadIdx.x] = m;
    sc[threadIdx.x] = c;
    __syncthreads();
    #pragma unroll
    for (int s = 128; s >= 1; s >>= 1) {
        if (threadIdx.x < (unsigned)s) {
            sm[threadIdx.x] += sm[threadIdx.x + s];
            sc[threadIdx.x] += sc[threadIdx.x + s];
        }
        __syncthreads();
    }
    if (threadIdx.x == 0) {
        const double mag_loss = sm[0] / NVOX;
        const double dir_loss = 1.0 - sc[0] / NVOX;
        out[0] = (float)(0.2 * (mag_loss + dir_loss));
    }
}

extern "C" void kernel_launch(void* const* d_in, const int* in_sizes, int n_in,
                              void* d_out, int out_size, void* d_ws, size_t ws_size,
                              hipStream_t stream) {
    const float* pred = (const float*)d_in[0];
    const float* targ = (const float*)d_in[1];
    float* out = (float*)d_out;
    float2* partial = (float2*)d_ws;  // 1000 * 8 B = 8 KB

    acl_partial<<<NBLOCKS, 256, 0, stream>>>(pred, targ, partial);
    acl_final<<<1, 256, 0, stream>>>(partial, out);
}